// Round 6
// baseline (1450.934 us; speedup 1.0000x reference)
//
#include <hip/hip_runtime.h>
#include <hip/hip_bf16.h>
#include <math.h>

// Problem dims (fixed by reference)
#define NTOK 98304      // 32768 * 3
#define DIN  256
#define DE   512
#define DH   512
#define DC   64
#define NCODE 1024
#define CHUNK 16384     // tokens per pipeline chunk (6 chunks)
#define DWCHUNK 1024    // tokens per dw block (skew-proof parallelism)

typedef _Float16 half8 __attribute__((ext_vector_type(8)));
typedef _Float16 half4 __attribute__((ext_vector_type(4)));
typedef float f32x4 __attribute__((ext_vector_type(4)));

__device__ __forceinline__ float gelu_f(float x) {
    const float k0 = 0.7978845608028654f;  // sqrt(2/pi)
    const float k1 = 0.044715f;
    float x3 = x * x * x;
    return 0.5f * x * (1.0f + tanhf(k0 * (x + k1 * x3)));
}

// async 16B global -> LDS (wave-uniform LDS base + lane*16)
__device__ __forceinline__ void glds16(const _Float16* g, _Float16* l) {
    __builtin_amdgcn_global_load_lds(
        (const __attribute__((address_space(1))) unsigned int*)(g),
        (__attribute__((address_space(3))) unsigned int*)(l), 16, 0, 0);
}

// ---------- prep kernels ----------
// W[K][N] fp32 -> hi/lo planes [N][K]
__global__ __launch_bounds__(256)
void transpose_split2(const float* __restrict__ W, _Float16* __restrict__ Wh,
                      _Float16* __restrict__ Wl, int K, int N)
{
    int e = blockIdx.x * 256 + threadIdx.x;
    if (e >= K * N) return;
    int k = e / N, n = e % N;
    float v = W[e];
    _Float16 h = (_Float16)v;
    _Float16 l = (_Float16)(v - (float)h);
    Wh[(size_t)n * K + k] = h;
    Wl[(size_t)n * K + k] = l;
}

// X fp32 -> hi/lo planes, same layout (4 elems/thread)
__global__ __launch_bounds__(256)
void split4(const float* __restrict__ X, _Float16* __restrict__ H,
            _Float16* __restrict__ L, int n4)
{
    int i = blockIdx.x * 256 + threadIdx.x;
    if (i >= n4) return;
    float4 v = ((const float4*)X)[i];
    float vv[4] = {v.x, v.y, v.z, v.w};
    half4 hh, ll;
#pragma unroll
    for (int j = 0; j < 4; ++j) {
        _Float16 h = (_Float16)vv[j];
        hh[j] = h;
        ll[j] = (_Float16)(vv[j] - (float)h);
    }
    *(half4*)(H + (size_t)i * 4) = hh;
    *(half4*)(L + (size_t)i * 4) = ll;
}

// emb [64][1024] fp32 -> planes [1024][64]
__global__ __launch_bounds__(256)
void prep_emb(const float* __restrict__ emb, _Float16* __restrict__ ebh,
              _Float16* __restrict__ ebl)
{
    int e = blockIdx.x * 256 + threadIdx.x;   // 65536
    int c = e >> 10, n = e & 1023;
    float v = emb[e];
    _Float16 h = (_Float16)v;
    _Float16 l = (_Float16)(v - (float)h);
    ebh[(size_t)n * DC + c] = h;
    ebl[(size_t)n * DC + c] = l;
}

__global__ __launch_bounds__(256)
void e2_kernel(const float* __restrict__ emb, float* __restrict__ e2)
{
    int n = blockIdx.x * 256 + threadIdx.x;   // 1024
    float s = 0.f;
#pragma unroll
    for (int c = 0; c < DC; ++c) { float e = emb[(size_t)c * NCODE + n]; s = fmaf(e, e, s); }
    e2[n] = s;
}

// ======================= MLP GEMM: planes + global_load_lds =======================
// C = gelu(A @ B^T + bias); A planes [M][K], B planes [N][K]. fp16x3 MFMA.
template<int BN, bool EMIT_LAT>
__global__ __launch_bounds__(256, 2)
void gemm_planes(const _Float16* __restrict__ Ahg, const _Float16* __restrict__ Alg,
                 const _Float16* __restrict__ Bhg, const _Float16* __restrict__ Blg,
                 const float* __restrict__ bias,
                 _Float16* __restrict__ Chg, _Float16* __restrict__ Clg,
                 float* __restrict__ Cf,
                 int M, int N, int K)
{
    constexpr int BM = 128, BK = 32;
    constexpr int WAVE_M = (BN == 128) ? 64 : 32;
    constexpr int MT = WAVE_M / 16;
    constexpr int NT = 4;
    constexpr int AG = BM / 64;   // glds insts per wave per A plane
    constexpr int BG = BN / 64;

    __shared__ _Float16 Ah[BM * 32], Al[BM * 32];
    __shared__ _Float16 Bh[BN * 32], Bl[BN * 32];

    const int tid  = threadIdx.x;
    const int lane = tid & 63, wid = tid >> 6;
    const int lm   = lane & 15, quad = lane >> 4;
    const int wave_m = (BN == 128) ? (wid & 1) * 64 : wid * 32;
    const int wave_n = (BN == 128) ? (wid >> 1) * 64 : 0;
    const int m0 = blockIdx.y * BM, n0 = blockIdx.x * BN;

    f32x4 acc[MT][NT];
#pragma unroll
    for (int mi = 0; mi < MT; ++mi)
#pragma unroll
        for (int ni = 0; ni < NT; ++ni) acc[mi][ni] = (f32x4)(0.f);

    for (int k0 = 0; k0 < K; k0 += BK) {
        // ---- async staging: raw 16B granules, no VALU repack ----
#pragma unroll
        for (int j = 0; j < AG; ++j) {
            int g = (wid * AG + j) * 64 + lane;
            int row = g >> 2, kc = (g & 3) * 8;
            size_t src = (size_t)(m0 + row) * K + k0 + kc;
            glds16(Ahg + src, &Ah[(size_t)(wid * AG + j) * 512]);
            glds16(Alg + src, &Al[(size_t)(wid * AG + j) * 512]);
        }
#pragma unroll
        for (int j = 0; j < BG; ++j) {
            int g = (wid * BG + j) * 64 + lane;
            int row = g >> 2, kc = (g & 3) * 8;
            size_t src = (size_t)(n0 + row) * K + k0 + kc;
            glds16(Bhg + src, &Bh[(size_t)(wid * BG + j) * 512]);
            glds16(Blg + src, &Bl[(size_t)(wid * BG + j) * 512]);
        }
        __syncthreads();

        half8 ahf[MT], alf[MT], bhf[NT], blf[NT];
#pragma unroll
        for (int mi = 0; mi < MT; ++mi) {
            int r = wave_m + mi * 16 + lm;
            ahf[mi] = *(const half8*)&Ah[r * 32 + quad * 8];
            alf[mi] = *(const half8*)&Al[r * 32 + quad * 8];
        }
#pragma unroll
        for (int ni = 0; ni < NT; ++ni) {
            int r = wave_n + ni * 16 + lm;
            bhf[ni] = *(const half8*)&Bh[r * 32 + quad * 8];
            blf[ni] = *(const half8*)&Bl[r * 32 + quad * 8];
        }
#pragma unroll
        for (int mi = 0; mi < MT; ++mi)
#pragma unroll
            for (int ni = 0; ni < NT; ++ni) {
                acc[mi][ni] = __builtin_amdgcn_mfma_f32_16x16x32_f16(ahf[mi], bhf[ni], acc[mi][ni], 0, 0, 0);
                acc[mi][ni] = __builtin_amdgcn_mfma_f32_16x16x32_f16(ahf[mi], blf[ni], acc[mi][ni], 0, 0, 0);
                acc[mi][ni] = __builtin_amdgcn_mfma_f32_16x16x32_f16(alf[mi], bhf[ni], acc[mi][ni], 0, 0, 0);
            }
        __syncthreads();
    }

    // epilogue: bias + gelu -> hi/lo planes (+ fp32 for latent layer)
#pragma unroll
    for (int ni = 0; ni < NT; ++ni) {
        int col = n0 + wave_n + ni * 16 + lm;
        float bv = bias[col];
#pragma unroll
        for (int mi = 0; mi < MT; ++mi) {
            int rowbase = m0 + wave_m + mi * 16 + quad * 4;
#pragma unroll
            for (int r = 0; r < 4; ++r) {
                float g = gelu_f(acc[mi][ni][r] + bv);
                size_t off = (size_t)(rowbase + r) * N + col;
                _Float16 h = (_Float16)g;
                Chg[off] = h;
                Clg[off] = (_Float16)(g - (float)h);
                if (EMIT_LAT) Cf[off] = g;
            }
        }
    }
}

// ======================= VQ main (fp16x4 MFMA distances) =======================
// 128 tokens/block, each wave 32 tokens x all 1024 codes (16 chunks of 64).
__global__ __launch_bounds__(256, 2)
void vq2_kernel(const _Float16* __restrict__ lath, const _Float16* __restrict__ latl,
                const float* __restrict__ lat, const float* __restrict__ emb,
                const _Float16* __restrict__ ebh, const _Float16* __restrict__ ebl,
                const float* __restrict__ e2,
                float* __restrict__ quant_out, float* __restrict__ encidx_out,
                int* __restrict__ codes_out, unsigned int* __restrict__ counts,
                float* __restrict__ sum_sq)
{
    __shared__ float e2s[NCODE];
    __shared__ int   sidx[128];
    __shared__ float wred[4];

    const int tid = threadIdx.x, lane = tid & 63, w = tid >> 6;
    const int lm = lane & 15, quad = lane >> 4;
    const int tok0 = blockIdx.x * 128;

    for (int i = tid; i < NCODE; i += 256) e2s[i] = e2[i];

    // A fragments straight from lat planes (token row, k = ks*32 + quad*8)
    half8 ah[2][2], al[2][2];
#pragma unroll
    for (int mi = 0; mi < 2; ++mi)
#pragma unroll
        for (int ks = 0; ks < 2; ++ks) {
            size_t src = (size_t)(tok0 + w * 32 + mi * 16 + lm) * DC + ks * 32 + quad * 8;
            ah[mi][ks] = *(const half8*)(lath + src);
            al[mi][ks] = *(const half8*)(latl + src);
        }
    __syncthreads();   // e2s ready

    float bd[2][4]; int bi[2][4];
#pragma unroll
    for (int mi = 0; mi < 2; ++mi)
#pragma unroll
        for (int r = 0; r < 4; ++r) { bd[mi][r] = INFINITY; bi[mi][r] = 0; }

    for (int k0 = 0; k0 < NCODE; k0 += 64) {
        f32x4 acc[2][4];
#pragma unroll
        for (int mi = 0; mi < 2; ++mi)
#pragma unroll
            for (int ni = 0; ni < 4; ++ni) acc[mi][ni] = (f32x4)(0.f);
#pragma unroll
        for (int ks = 0; ks < 2; ++ks) {
#pragma unroll
            for (int ni = 0; ni < 4; ++ni) {
                size_t src = (size_t)(k0 + ni * 16 + lm) * DC + ks * 32 + quad * 8;
                half8 bh = *(const half8*)(ebh + src);
                half8 bl = *(const half8*)(ebl + src);
#pragma unroll
                for (int mi = 0; mi < 2; ++mi) {
                    acc[mi][ni] = __builtin_amdgcn_mfma_f32_16x16x32_f16(ah[mi][ks], bh, acc[mi][ni], 0, 0, 0);
                    acc[mi][ni] = __builtin_amdgcn_mfma_f32_16x16x32_f16(ah[mi][ks], bl, acc[mi][ni], 0, 0, 0);
                    acc[mi][ni] = __builtin_amdgcn_mfma_f32_16x16x32_f16(al[mi][ks], bh, acc[mi][ni], 0, 0, 0);
                    acc[mi][ni] = __builtin_amdgcn_mfma_f32_16x16x32_f16(al[mi][ks], bl, acc[mi][ni], 0, 0, 0);
                }
            }
        }
#pragma unroll
        for (int ni = 0; ni < 4; ++ni) {
            float ee = e2s[k0 + ni * 16 + lm];
            int code = k0 + ni * 16 + lm;
#pragma unroll
            for (int mi = 0; mi < 2; ++mi)
#pragma unroll
                for (int r = 0; r < 4; ++r) {
                    float d = ee - 2.f * acc[mi][ni][r];
                    if (d < bd[mi][r]) { bd[mi][r] = d; bi[mi][r] = code; }  // ascending codes => first-min
                }
        }
    }

    // cross-lm butterfly argmin (lexicographic (d, idx) => first occurrence)
#pragma unroll
    for (int mi = 0; mi < 2; ++mi)
#pragma unroll
        for (int r = 0; r < 4; ++r) {
            float d = bd[mi][r]; int i = bi[mi][r];
#pragma unroll
            for (int m = 1; m < 16; m <<= 1) {
                float d2 = __shfl_xor(d, m);
                int   i2 = __shfl_xor(i, m);
                if (d2 < d || (d2 == d && i2 < i)) { d = d2; i = i2; }
            }
            if (lm == 0) {
                int tl = w * 32 + mi * 16 + quad * 4 + r;
                sidx[tl] = i;
                encidx_out[tok0 + tl] = (float)i;
                codes_out[tok0 + tl] = i;
                atomicAdd(&counts[i], 1u);
            }
        }
    __syncthreads();

    // phase 2: quantized gather (exact fp32 emb), loss partial
    float lsum = 0.f;
#pragma unroll
    for (int p = 0; p < 2; ++p) {
        int t2 = (tid >> 2) + p * 64;
        int g  = tid & 3;
        int code = sidx[t2];
#pragma unroll
        for (int q = 0; q < 4; ++q) {
            int c0 = g * 16 + q * 4;
            float4 xv = *(const float4*)(lat + (size_t)(tok0 + t2) * DC + c0);
            float xx[4] = {xv.x, xv.y, xv.z, xv.w};
            float qv[4];
#pragma unroll
            for (int j = 0; j < 4; ++j) {
                qv[j] = emb[(size_t)(c0 + j) * NCODE + code];
                float df = qv[j] - xx[j];
                lsum = fmaf(df, df, lsum);
            }
            float4 v; v.x = qv[0]; v.y = qv[1]; v.z = qv[2]; v.w = qv[3];
            *(float4*)(quant_out + (size_t)(tok0 + t2) * DC + c0) = v;
        }
    }
#pragma unroll
    for (int o = 32; o > 0; o >>= 1) lsum += __shfl_down(lsum, o);
    if ((tid & 63) == 0) wred[tid >> 6] = lsum;
    __syncthreads();
    if (tid == 0) atomicAdd(sum_sq, wred[0] + wred[1] + wred[2] + wred[3]);
}

// ======================= dw via skew-proof bucketing =======================
__global__ __launch_bounds__(1024)
void scan_kernel(const unsigned int* __restrict__ counts, int* __restrict__ offs,
                 unsigned int* __restrict__ cursors)
{
    __shared__ int s[1024];
    int t = threadIdx.x;
    int v = (int)counts[t];
    s[t] = v; __syncthreads();
    for (int d = 1; d < 1024; d <<= 1) {
        int x = (t >= d) ? s[t - d] : 0;
        __syncthreads();
        s[t] += x;
        __syncthreads();
    }
    offs[t] = s[t] - v;
    cursors[t] = (unsigned int)(s[t] - v);
}

__global__ __launch_bounds__(256)
void scatter_kernel(const int* __restrict__ codes, unsigned int* __restrict__ cursors,
                    int* __restrict__ bucket)
{
    __shared__ unsigned int hist[NCODE];
    __shared__ unsigned int basea[NCODE];
    int tid = threadIdx.x;
    for (int i = tid; i < NCODE; i += 256) hist[i] = 0;
    __syncthreads();
    int t = blockIdx.x * 256 + tid;
    int c = codes[t];
    unsigned int rank = atomicAdd(&hist[c], 1u);
    __syncthreads();
    for (int i = tid; i < NCODE; i += 256) {
        unsigned int h = hist[i];
        if (h > 0) basea[i] = atomicAdd(&cursors[i], h);
    }
    __syncthreads();
    bucket[basea[c] + rank] = t;
}

__global__ __launch_bounds__(256)
void dw_kernel(const float* __restrict__ lat, const int* __restrict__ bucket,
               const int* __restrict__ offs, const unsigned int* __restrict__ counts,
               float* __restrict__ dw)
{
    __shared__ float sred[4][64];
    const int code = blockIdx.x;
    const int n = (int)counts[code];
    const int start = blockIdx.y * DWCHUNK;
    if (start >= n) return;
    const int cnt = min(n - start, DWCHUNK);
    const int base = offs[code] + start;
    const int lane = threadIdx.x & 63, wave = threadIdx.x >> 6;

    float s0 = 0.f, s1 = 0.f, s2 = 0.f, s3 = 0.f;
    int i = wave;
    for (; i + 12 < cnt; i += 16) {
        int t0 = bucket[base + i];
        int t1 = bucket[base + i + 4];
        int t2 = bucket[base + i + 8];
        int t3 = bucket[base + i + 12];
        s0 += lat[(size_t)t0 * DC + lane];
        s1 += lat[(size_t)t1 * DC + lane];
        s2 += lat[(size_t)t2 * DC + lane];
        s3 += lat[(size_t)t3 * DC + lane];
    }
    for (; i < cnt; i += 4)
        s0 += lat[(size_t)bucket[base + i] * DC + lane];

    sred[wave][lane] = (s0 + s1) + (s2 + s3);
    __syncthreads();
    if (threadIdx.x < 64) {
        float tot = sred[0][lane] + sred[1][lane] + sred[2][lane] + sred[3][lane];
        atomicAdd(&dw[(size_t)lane * NCODE + code], tot);
    }
}

// ======================= finalize =======================
__global__ __launch_bounds__(1024)
void finalize_kernel(const unsigned int* __restrict__ counts,
                     const float* __restrict__ dw,
                     const float* __restrict__ ema_ch,
                     const float* __restrict__ ema_dw,
                     const float* __restrict__ sum_sq,
                     float* __restrict__ out_loss, float* __restrict__ out_perp,
                     float* __restrict__ out_newemb)
{
    __shared__ float sred[1024];
    const int k = threadIdx.x;
    const float debias = (float)(1.0 - pow(0.99, 1001.0));
    float cnt = (float)counts[k];
    float cs  = (ema_ch[k] * 0.99f + cnt * 0.01f) / debias;

    sred[k] = cs; __syncthreads();
    for (int s = 512; s > 0; s >>= 1) { if (k < s) sred[k] += sred[k + s]; __syncthreads(); }
    float n = sred[0];
    __syncthreads();

    float p = cnt / 98304.0f;
    sred[k] = p * logf(p + 1e-10f);
    __syncthreads();
    for (int s = 512; s > 0; s >>= 1) { if (k < s) sred[k] += sred[k + s]; __syncthreads(); }
    if (k == 0) {
        out_perp[0] = expf(-sred[0]);
        out_loss[0] = 0.25f * sum_sq[0] / 6291456.0f;
    }

    float stable = (cs + 1e-5f) / (n + 1024.0f * 1e-5f) * n;
#pragma unroll
    for (int c = 0; c < 64; ++c) {
        size_t o = (size_t)c * 1024 + k;
        out_newemb[o] = ((ema_dw[o] * 0.99f + dw[o] * 0.01f) / debias) / stable;
    }
}

extern "C" void kernel_launch(void* const* d_in, const int* in_sizes, int n_in,
                              void* d_out, int out_size, void* d_ws, size_t ws_size,
                              hipStream_t stream)
{
    (void)in_sizes; (void)n_in; (void)out_size; (void)ws_size;
    const float* states = (const float*)d_in[0];
    const float* w_se   = (const float*)d_in[1];
    const float* b_se   = (const float*)d_in[2];
    const float* w0     = (const float*)d_in[3];
    const float* b0     = (const float*)d_in[4];
    const float* w1     = (const float*)d_in[5];
    const float* b1     = (const float*)d_in[6];
    const float* w2     = (const float*)d_in[7];
    const float* b2     = (const float*)d_in[8];
    const float* emb    = (const float*)d_in[9];
    const float* ema_ch = (const float*)d_in[10];
    const float* ema_dw = (const float*)d_in[11];

    float* out        = (float*)d_out;
    float* q_out      = out;
    float* loss_out   = out + 6291456;
    float* perp_out   = out + 6291457;
    float* idx_out    = out + 6291458;
    float* newemb_out = out + 6389762;

    // ---- workspace layout (zeroed prefix first) ----
    char* ws = (char*)d_ws;
    size_t o = 0;
    unsigned int* counts  = (unsigned int*)(ws + o); o += 4096;
    unsigned int* cursors = (unsigned int*)(ws + o); o += 4096;
    float*        sumsq   = (float*)(ws + o);        o += 256;
    float*        dwb     = (float*)(ws + o);        o += (size_t)DC * NCODE * 4;
    const size_t ZERO_BYTES = o;
    int*          offs    = (int*)(ws + o);          o += 4096;
    int*          codes   = (int*)(ws + o);          o += (size_t)NTOK * 4;
    int*          bucket  = (int*)(ws + o);          o += (size_t)NTOK * 4;
    float*        e2b     = (float*)(ws + o);        o += 4096;
    _Float16*     ebh     = (_Float16*)(ws + o);     o += (size_t)NCODE * DC * 2;
    _Float16*     ebl     = (_Float16*)(ws + o);     o += (size_t)NCODE * DC * 2;
    _Float16*     wse_h   = (_Float16*)(ws + o);     o += (size_t)DIN * DE * 2;
    _Float16*     wse_l   = (_Float16*)(ws + o);     o += (size_t)DIN * DE * 2;
    _Float16*     w0h     = (_Float16*)(ws + o);     o += (size_t)DE * DH * 2;
    _Float16*     w0l     = (_Float16*)(ws + o);     o += (size_t)DE * DH * 2;
    _Float16*     w1h     = (_Float16*)(ws + o);     o += (size_t)DH * DH * 2;
    _Float16*     w1l     = (_Float16*)(ws + o);     o += (size_t)DH * DH * 2;
    _Float16*     w2h     = (_Float16*)(ws + o);     o += (size_t)DH * DC * 2;
    _Float16*     w2l     = (_Float16*)(ws + o);     o += (size_t)DH * DC * 2;
    _Float16*     stm_h   = (_Float16*)(ws + o);     o += (size_t)CHUNK * DIN * 2;
    _Float16*     stm_l   = (_Float16*)(ws + o);     o += (size_t)CHUNK * DIN * 2;
    _Float16*     aA_h    = (_Float16*)(ws + o);     o += (size_t)CHUNK * DE * 2;
    _Float16*     aA_l    = (_Float16*)(ws + o);     o += (size_t)CHUNK * DE * 2;
    _Float16*     aB_h    = (_Float16*)(ws + o);     o += (size_t)CHUNK * DH * 2;
    _Float16*     aB_l    = (_Float16*)(ws + o);     o += (size_t)CHUNK * DH * 2;
    _Float16*     lath    = (_Float16*)(ws + o);     o += (size_t)NTOK * DC * 2;
    _Float16*     latl    = (_Float16*)(ws + o);     o += (size_t)NTOK * DC * 2;
    float*        lat     = (float*)(ws + o);        o += (size_t)NTOK * DC * 4;

    hipMemsetAsync(d_ws, 0, ZERO_BYTES, stream);

    // prep (tiny)
    transpose_split2<<<dim3((DIN * DE + 255) / 256), dim3(256), 0, stream>>>(w_se, wse_h, wse_l, DIN, DE);
    transpose_split2<<<dim3((DE * DH + 255) / 256), dim3(256), 0, stream>>>(w0, w0h, w0l, DE, DH);
    transpose_split2<<<dim3((DH * DH + 255) / 256), dim3(256), 0, stream>>>(w1, w1h, w1l, DH, DH);
    transpose_split2<<<dim3((DH * DC + 255) / 256), dim3(256), 0, stream>>>(w2, w2h, w2l, DH, DC);
    prep_emb<<<dim3(256), dim3(256), 0, stream>>>(emb, ebh, ebl);
    e2_kernel<<<dim3(4), dim3(256), 0, stream>>>(emb, e2b);

    dim3 blk(256);
    const int MBLK = CHUNK / 128;
    for (int c = 0; c < NTOK / CHUNK; ++c) {
        size_t off = (size_t)c * CHUNK;
        split4<<<dim3(CHUNK * DIN / 4 / 256), blk, 0, stream>>>(
            states + off * DIN, stm_h, stm_l, CHUNK * DIN / 4);
        gemm_planes<128, false><<<dim3(DE / 128, MBLK), blk, 0, stream>>>(
            stm_h, stm_l, wse_h, wse_l, b_se, aA_h, aA_l, (float*)nullptr, CHUNK, DE, DIN);
        gemm_planes<128, false><<<dim3(DH / 128, MBLK), blk, 0, stream>>>(
            aA_h, aA_l, w0h, w0l, b0, aB_h, aB_l, (float*)nullptr, CHUNK, DH, DE);
        gemm_planes<128, false><<<dim3(DH / 128, MBLK), blk, 0, stream>>>(
            aB_h, aB_l, w1h, w1l, b1, aA_h, aA_l, (float*)nullptr, CHUNK, DH, DH);
        gemm_planes<64, true><<<dim3(1, MBLK), blk, 0, stream>>>(
            aA_h, aA_l, w2h, w2l, b2, lath + off * DC, latl + off * DC,
            lat + off * DC, CHUNK, DC, DH);
    }

    vq2_kernel<<<dim3(NTOK / 128), blk, 0, stream>>>(
        lath, latl, lat, emb, ebh, ebl, e2b, q_out, idx_out, codes, counts, sumsq);

    scan_kernel<<<dim3(1), dim3(1024), 0, stream>>>(counts, offs, cursors);
    scatter_kernel<<<dim3(NTOK / 256), blk, 0, stream>>>(codes, cursors, bucket);
    dw_kernel<<<dim3(NCODE, NTOK / DWCHUNK), blk, 0, stream>>>(lat, bucket, offs, counts, dwb);

    finalize_kernel<<<dim3(1), dim3(1024), 0, stream>>>(counts, dwb, ema_ch, ema_dw, sumsq,
                                                        loss_out, perp_out, newemb_out);
}